// Round 3
// baseline (544.205 us; speedup 1.0000x reference)
//
#include <hip/hip_runtime.h>

#define Bn 128
#define Sn 512
#define Hn 1024
#define Ln 4

typedef float nfloat4 __attribute__((ext_vector_type(4)));

__device__ __forceinline__ float sigmoidf_(float x) { return 1.0f / (1.0f + __expf(-x)); }

// ---------------- K1: fused lengths + stable descending argsort (1 block) ----------------
__global__ __launch_bounds__(1024) void lensort_kernel(const int* __restrict__ x,
                                                       int* __restrict__ lengths,
                                                       int* __restrict__ rank,
                                                       int* __restrict__ tok_sorted,
                                                       int* __restrict__ bs_last) {
  __shared__ int pc[128][8];
  __shared__ int sl[128];
  __shared__ int cnt;
  const int t = threadIdx.x;
  const int row = t >> 3, seg = t & 7;
  // phase 1: count x>0 per row (8 threads per row, 16 int4 each)
  int c = 0;
  const int4* xp = (const int4*)x + row * 128 + seg * 16;
#pragma unroll
  for (int i = 0; i < 16; i++) {
    int4 v = xp[i];
    c += (v.x > 0) + (v.y > 0) + (v.z > 0) + (v.w > 0);
  }
  pc[row][seg] = c;
  if (t == 0) cnt = 0;
  __syncthreads();
  // phase 2: lengths, rank, sorted first tokens, bs_last (threads 0..127)
  int len = 0;
  if (t < 128) {
#pragma unroll
    for (int i = 0; i < 8; i++) len += pc[t][i];
    sl[t] = len;
    lengths[t] = len;
  }
  __syncthreads();
  if (t < 128) {
    int r = 0;
    for (int b2 = 0; b2 < 128; b2++) {
      int l2 = sl[b2];
      r += (l2 > len) || (l2 == len && b2 < t);
    }
    rank[t] = r;                 // unsort_idx[t]
    tok_sorted[r] = x[t * Sn];   // x[sorted_idx[r], 0]
    if (len >= Sn) atomicAdd(&cnt, 1);
  }
  __syncthreads();
  if (t == 0) bs_last[0] = cnt;
}

// ---------------- K2: split-K GEMM for gates i,g,o (f skipped: f*c0 == 0) ----------------
// grid = 32 m-tiles x 8 k-chunks = 256 blocks, 320 threads:
//   waves 0-3 (t<256): compute, exactly as before.
//   wave 4 (t>=256): dedicated zero-tail writer for the output region t in [32,512),
//     layer l covers t in [32+l*120, 32+(l+1)*120), half = blockIdx>>7 picks 60 rows.
//     Uses raw s_barrier (no implicit vmcnt(0) drain) so NT stores stay fully async.
// part region = out[t<24] slabs; zero writes start at t=32 -> disjoint.
__global__ __launch_bounds__(320) void gemm_kernel(const float* __restrict__ xt,
                                                   const int* __restrict__ tok,
                                                   const float* __restrict__ Wl,
                                                   float* __restrict__ part,
                                                   const int* __restrict__ lengths,
                                                   float* __restrict__ out,
                                                   const int layer) {
  __shared__ float xtT[32][132];  // [kk][r], stride 132 keeps 16B alignment for b128 reads
  __shared__ float Ws[32][96];    // [kk][q*32 + mloc]
  __shared__ int sTok[128];
  const int t = threadIdx.x;
  const int mtile = blockIdx.x & 31;
  const int kc = blockIdx.x >> 5;

  if (tok != nullptr) {        // uniform branch; layer 0 only
    if (t < 128) sTok[t] = tok[t];
    __syncthreads();
  }

  if (t >= 256) {
    // ---------------- zero-store wave ----------------
    const int lane = t - 256;           // 0..63
    const int b = blockIdx.x & 127;
    const int half = blockIdx.x >> 7;   // 0..1
    const int len = lengths[b];
    const int tw0 = 32 + layer * 120 + half * 60;
    const nfloat4 z = (nfloat4)0.0f;
#pragma unroll
    for (int tile = 0; tile < 4; tile++) {
      __builtin_amdgcn_s_barrier();     // matches compute-wave barrier A
      const int r0 = tw0 + tile * 15;
      for (int i = 0; i < 15; i++) {
        const int tt = r0 + i;
        if (tt >= len) {
          nfloat4* p = (nfloat4*)out + ((size_t)tt * 128 + b) * 256 + lane * 4;
          __builtin_nontemporal_store(z, p + 0);
          __builtin_nontemporal_store(z, p + 1);
          __builtin_nontemporal_store(z, p + 2);
          __builtin_nontemporal_store(z, p + 3);
        }
      }
      __builtin_amdgcn_s_barrier();     // matches compute-wave barrier B
    }
    return;
  }

  // ---------------- compute waves (t < 256) ----------------
  const int rg = t & 31;
  const int msub = t >> 5;     // 0..7 -> m_loc = msub*4..+3
  const int k0 = kc * 128;
  const int kv4 = (t & 7) * 4;

  const float* xrow[4];
#pragma unroll
  for (int i = 0; i < 4; i++) {
    const int r = i * 32 + (t >> 3);
    const int row = (tok != nullptr) ? sTok[r] : r;
    xrow[i] = xt + (size_t)row * 1024;
  }

  float acc[3][4][4];
#pragma unroll
  for (int q = 0; q < 3; q++)
#pragma unroll
    for (int mm = 0; mm < 4; mm++)
#pragma unroll
      for (int rr = 0; rr < 4; rr++) acc[q][mm][rr] = 0.0f;

  float4 xreg[4], wreg[3];
  // prologue: load tile 0 into registers
  {
#pragma unroll
    for (int i = 0; i < 4; i++) xreg[i] = *(const float4*)&xrow[i][k0 + kv4];
#pragma unroll
    for (int i = 0; i < 3; i++) {
      int jj = i * 32 + (t >> 3);
      int q = jj >> 5, mloc = jj & 31;
      int qoff = (q == 0) ? 0 : ((q == 1) ? 2048 : 3072);  // gate rows: i, g, o
      wreg[i] = *(const float4*)&Wl[(size_t)(qoff + mtile * 32 + mloc) * 1024 + k0 + kv4];
    }
  }

#pragma unroll
  for (int tile = 0; tile < 4; tile++) {
    __syncthreads();                    // barrier A
    // registers -> LDS (transposed)
#pragma unroll
    for (int i = 0; i < 4; i++) {
      const int r = i * 32 + (t >> 3);
      xtT[kv4 + 0][r] = xreg[i].x;
      xtT[kv4 + 1][r] = xreg[i].y;
      xtT[kv4 + 2][r] = xreg[i].z;
      xtT[kv4 + 3][r] = xreg[i].w;
    }
#pragma unroll
    for (int i = 0; i < 3; i++) {
      const int jj = i * 32 + (t >> 3);
      Ws[kv4 + 0][jj] = wreg[i].x;
      Ws[kv4 + 1][jj] = wreg[i].y;
      Ws[kv4 + 2][jj] = wreg[i].z;
      Ws[kv4 + 3][jj] = wreg[i].w;
    }
    // prefetch next tile while computing this one
    float4 xnxt[4], wnxt[3];
    if (tile < 3) {
      const int kt = k0 + (tile + 1) * 32;
#pragma unroll
      for (int i = 0; i < 4; i++) xnxt[i] = *(const float4*)&xrow[i][kt + kv4];
#pragma unroll
      for (int i = 0; i < 3; i++) {
        int jj = i * 32 + (t >> 3);
        int q = jj >> 5, mloc = jj & 31;
        int qoff = (q == 0) ? 0 : ((q == 1) ? 2048 : 3072);
        wnxt[i] = *(const float4*)&Wl[(size_t)(qoff + mtile * 32 + mloc) * 1024 + kt + kv4];
      }
    }
    __syncthreads();                    // barrier B
#pragma unroll
    for (int kk = 0; kk < 32; kk++) {
      const float4 xv = *(const float4*)&xtT[kk][rg * 4];
      const float4 w0 = *(const float4*)&Ws[kk][msub * 4];
      const float4 w1 = *(const float4*)&Ws[kk][32 + msub * 4];
      const float4 w2 = *(const float4*)&Ws[kk][64 + msub * 4];
      const float xa[4] = {xv.x, xv.y, xv.z, xv.w};
      const float wv[3][4] = {{w0.x, w0.y, w0.z, w0.w},
                              {w1.x, w1.y, w1.z, w1.w},
                              {w2.x, w2.y, w2.z, w2.w}};
#pragma unroll
      for (int q = 0; q < 3; q++)
#pragma unroll
        for (int mm = 0; mm < 4; mm++)
#pragma unroll
          for (int rr = 0; rr < 4; rr++)
            acc[q][mm][rr] = fmaf(wv[q][mm], xa[rr], acc[q][mm][rr]);
    }
    if (tile < 3) {
#pragma unroll
      for (int i = 0; i < 4; i++) xreg[i] = xnxt[i];
#pragma unroll
      for (int i = 0; i < 3; i++) wreg[i] = wnxt[i];
    }
  }

  const int mbase = mtile * 32 + msub * 4;
#pragma unroll
  for (int q = 0; q < 3; q++)
#pragma unroll
    for (int mm = 0; mm < 4; mm++) {
      float4 v = make_float4(acc[q][mm][0], acc[q][mm][1], acc[q][mm][2], acc[q][mm][3]);
      *(float4*)&part[(((size_t)kc * 3 + q) * 1024 + (mbase + mm)) * 128 + rg * 4] = v;
    }
}

// ---------------- K3: reduce partials + biases, activations, states ----------------
// grid = 256 blocks (4 m each), 128 threads (thread = one sorted row r).
// NOTE: m0 = blockIdx.x*4 spans exactly m in [0,1024) at grid=256 — do NOT raise the
// grid without shrinking per-block m-extent (768 blocks overflowed xt_out/sh/sc in R2).
__global__ __launch_bounds__(128) void act_kernel(const float* __restrict__ part,
                                                  const float* __restrict__ bih,
                                                  const float* __restrict__ bhh,
                                                  const int* __restrict__ bs_last,
                                                  float* __restrict__ xt_out,
                                                  float* __restrict__ sh,
                                                  float* __restrict__ sc) {
  const int r = threadIdx.x;          // 0..127
  const int m0 = blockIdx.x * 4;
  const int bs = bs_last[0];
  float hv[4], cv[4];
#pragma unroll
  for (int mm = 0; mm < 4; mm++) {
    const int m = m0 + mm;
    float si = 0.f, sg = 0.f, so = 0.f;
#pragma unroll
    for (int kc = 0; kc < 8; kc++) {
      const float* p = part + (((size_t)kc * 3) * 1024 + m) * 128 + r;
      si += p[0];
      sg += p[(size_t)1024 * 128];
      so += p[(size_t)2048 * 128];
    }
    si += bih[m] + bhh[m];
    sg += bih[2048 + m] + bhh[2048 + m];
    so += bih[3072 + m] + bhh[3072 + m];
    const float c = sigmoidf_(si) * tanhf(sg);
    const float h = sigmoidf_(so) * tanhf(c);
    hv[mm] = h;
    cv[mm] = c;
  }
  const float msk = (r < bs) ? 1.0f : 0.0f;
  *(float4*)&xt_out[(size_t)r * 1024 + m0] = make_float4(hv[0], hv[1], hv[2], hv[3]);
  *(float4*)&sh[(size_t)r * 1024 + m0] =
      make_float4(msk * hv[0], msk * hv[1], msk * hv[2], msk * hv[3]);
  *(float4*)&sc[(size_t)r * 1024 + m0] =
      make_float4(msk * cv[0], msk * cv[1], msk * cv[2], msk * cv[3]);
}

// ---------------- K4: output valid region only (zeros t>=32 already written by gemm waves) ----
// grid = 128 b x 8 t-chunks (64 t each). Writes h rows for t < len[b]; chunk 0 also
// covers the residual zero band t in [len, 32) when len < 32 (part overlap region).
__global__ __launch_bounds__(256) void bcast_kernel(const float* __restrict__ hfin,
                                                    const int* __restrict__ lengths,
                                                    const int* __restrict__ rank,
                                                    float* __restrict__ out) {
  const int b = blockIdx.x & 127;
  const int c = blockIdx.x >> 7;      // 0..7
  const int len = lengths[b];
  const int t0 = c * 64;
  if (t0 < len) {
    const nfloat4 v = ((const nfloat4*)hfin)[rank[b] * 256 + threadIdx.x];
    const int hi = (len < t0 + 64) ? len : (t0 + 64);
    nfloat4* p = (nfloat4*)out + ((size_t)t0 * 128 + b) * 256 + threadIdx.x;
    for (int tt = t0; tt < hi; tt++) {
      __builtin_nontemporal_store(v, p);
      p += 32768;                      // one t step = 128*1024 floats
    }
  }
  if (c == 0 && len < 32) {
    const nfloat4 z = (nfloat4)0.0f;
    nfloat4* pz = (nfloat4*)out + ((size_t)len * 128 + b) * 256 + threadIdx.x;
    for (int tt = len; tt < 32; tt++) {
      __builtin_nontemporal_store(z, pz);
      pz += 32768;
    }
  }
}

extern "C" void kernel_launch(void* const* d_in, const int* in_sizes, int n_in,
                              void* d_out, int out_size, void* d_ws, size_t ws_size,
                              hipStream_t stream) {
  const int* x = (const int*)d_in[0];
  const float* emb = (const float*)d_in[1];
  const float* W_ih = (const float*)d_in[2];
  // d_in[3] = W_hh: NEVER multiplied (h0 == 0); only b_hh is added.
  const float* b_ih = (const float*)d_in[4];
  const float* b_hh = (const float*)d_in[5];

  float* out = (float*)d_out;
  float* sh = out + (size_t)Sn * Bn * Hn;   // state_h [L,B,H]
  float* sc = sh + (size_t)Ln * Bn * Hn;    // state_c [L,B,H]
  float* part = out;                        // 12.58 MB GEMM-partial scratch = out t-slabs [0,24);
                                            // gemm zero-waves only touch t>=32; bcast rewrites t<32.

  char* ws = (char*)d_ws;
  int* lengths = (int*)ws;                  // [128]
  int* rank = lengths + 128;                // [128]
  int* tok_sorted = rank + 128;             // [128]
  int* bs_last = tok_sorted + 128;          // [1]
  float* xtA = (float*)(ws + 4096);         // [128,1024]
  float* xtB = xtA + 128 * 1024;            // [128,1024]

  lensort_kernel<<<1, 1024, 0, stream>>>(x, lengths, rank, tok_sorted, bs_last);

  // layer 0 consumes emb rows gathered via tok_sorted directly
  float* bufs[2] = {xtA, xtB};
  const float* xin = emb;
  const int* tokp = tok_sorted;
  for (int l = 0; l < Ln; l++) {
    gemm_kernel<<<256, 320, 0, stream>>>(xin, tokp, W_ih + (size_t)l * 4 * Hn * Hn, part,
                                         lengths, out, l);
    act_kernel<<<256, 128, 0, stream>>>(part, b_ih + l * 4 * Hn, b_hh + l * 4 * Hn, bs_last,
                                        bufs[l & 1], sh + (size_t)l * Bn * Hn,
                                        sc + (size_t)l * Bn * Hn);
    xin = bufs[l & 1];
    tokp = nullptr;
  }
  // after the loop, xin == xtB holds the top-layer h (sorted order)
  bcast_kernel<<<1024, 256, 0, stream>>>(xin, lengths, rank, out);
}